// Round 3
// baseline (367.732 us; speedup 1.0000x reference)
//
#include <hip/hip_runtime.h>
#include <hip/hip_bf16.h>
#include <math.h>

typedef __bf16 bf16x8 __attribute__((ext_vector_type(8)));
typedef __bf16 bf16x4 __attribute__((ext_vector_type(4)));
typedef float  f32x4  __attribute__((ext_vector_type(4)));

#define HD  64
#define NQT 32   // number of 64-row q tiles (N/64)
// element-space XOR swizzle for 128B-stride rows (== byte ^ ((row&7)<<4))
#define SWZ(r, c) ((c) ^ (((r) & 7) << 3))

__global__ __launch_bounds__(512, 4)
void fattn_fwd(const float* __restrict__ Q, const float* __restrict__ K,
               const float* __restrict__ V, const int* __restrict__ causal_p,
               float* __restrict__ O, int B, int N, int H) {
  // two KV-parity groups, each with its own K/V/P tile set; union'd with the
  // f32 merge scratch used in the epilogue (both 48 KiB)
  __shared__ union SMem {
    struct { __bf16 K[2][64][64]; __bf16 V[2][64][64]; __bf16 P[2][64][64]; } t;
    float mrg[24][2][256];   // [slot][qi][w4*64+lane]
  } sm;

  const int tid  = threadIdx.x;
  const int w    = tid >> 6;     // 0..7
  const int g    = w >> 2;       // KV parity group
  const int w4   = w & 3;        // wave within group
  const int lane = tid & 63;
  const int lo = lane & 15, hi = lane >> 4;
  const int t256 = tid & 255;

  // XCD swizzle: 64 consecutive logical blocks (4 bh, all pairs) per XCD
  const int flat = (blockIdx.x & 7) * 64 + (blockIdx.x >> 3);
  const int xA = flat & 15;            // pair index
  const int bh = flat >> 4;
  const int xB = NQT - 1 - xA;         // partner tile -> uniform 33 units/block
  const int bb = bh / H, hh = bh - bb * H;

  const int causal = causal_p[0];
  const int sN = H * HD;

  const float* Qb = Q + (long)bb * N * sN + hh * HD;
  const float* Kb = K + (long)bb * N * sN + hh * HD;
  const float* Vb = V + (long)bb * N * sN + hh * HD;
  float*       Ob = O + (long)bb * N * sN + hh * HD;

  const int tmaxA = causal ? xA : (NQT - 1);
  const int tmaxB = causal ? xB : (NQT - 1);   // >= 16 always

  // ---- Q fragments, scaled by 1/sqrt(d)*log2(e) (exp2-domain softmax) ----
  const float qscale = 0.125f * 1.44269504088896340736f;
  bf16x8 aq[2][2];
#pragma unroll
  for (int qi = 0; qi < 2; ++qi) {
    const int q0q = ((qi == 0) ? xA : xB) * 64;
    const float* qp = Qb + (long)(q0q + w4 * 16 + lo) * sN;
#pragma unroll
    for (int c = 0; c < 2; ++c) {
      f32x4 x0 = *(const f32x4*)(qp + c * 32 + hi * 8);
      f32x4 x1 = *(const f32x4*)(qp + c * 32 + hi * 8 + 4);
      bf16x8 a;
#pragma unroll
      for (int j = 0; j < 4; ++j) {
        a[j]     = (__bf16)(x0[j] * qscale);
        a[j + 4] = (__bf16)(x1[j] * qscale);
      }
      aq[qi][c] = a;
    }
  }

  f32x4 acc[2][4];
  float m_run[2][4], l_run[2][4];
#pragma unroll
  for (int qi = 0; qi < 2; ++qi)
#pragma unroll
    for (int i = 0; i < 4; ++i) {
      acc[qi][i] = (f32x4){0.f, 0.f, 0.f, 0.f};
      m_run[qi][i] = -INFINITY;
      l_run[qi][i] = 0.f;
    }

  // ---- staging: each group stages its own parity's tiles ----
  f32x4 kreg[4], vreg[4];
  auto issue = [&](int tt) {
    const int k0 = tt * 64;
#pragma unroll
    for (int i = 0; i < 4; ++i) {
      const int fl = t256 + i * 256;
      const int r = fl >> 4, c4 = (fl & 15) * 4;
      kreg[i] = *(const f32x4*)(Kb + (long)(k0 + r) * sN + c4);
    }
    // V: lane owns a 4x4 (kv x d) block -> free in-register transpose
    const float* vrow = Vb + (long)(k0 + w4 * 16 + hi * 4) * sN + lo * 4;
#pragma unroll
    for (int q = 0; q < 4; ++q) vreg[q] = *(const f32x4*)(vrow + (long)q * sN);
  };
  auto wr = [&]() {
#pragma unroll
    for (int i = 0; i < 4; ++i) {
      const int fl = t256 + i * 256;
      const int r = fl >> 4, c4 = (fl & 15) * 4;
      bf16x4 kb;
#pragma unroll
      for (int j = 0; j < 4; ++j) kb[j] = (__bf16)kreg[i][j];
      *(bf16x4*)&sm.t.K[g][r][SWZ(r, c4)] = kb;
    }
#pragma unroll
    for (int j = 0; j < 4; ++j) {
      const int d = lo * 4 + j;
      bf16x4 vv;
#pragma unroll
      for (int q = 0; q < 4; ++q) vv[q] = (__bf16)vreg[q][j];
      *(bf16x4*)&sm.t.V[g][d][SWZ(d, w4 * 16 + hi * 4)] = vv;
    }
  };

  // prologue: group g stages tile g
  issue(g);
  wr();
  __syncthreads();

  const int niter = (tmaxB >> 1) + 1;
  for (int i = 0; i < niter; ++i) {
    const int tg = 2 * i + g;
    const bool active = (tg <= tmaxB);
    const bool pf = (tg + 2 <= tmaxB);
    if (pf) issue(tg + 2);   // HBM latency hides under compute below

    if (active) {
      const int k0 = tg * 64;
#pragma unroll
      for (int qi = 0; qi < 2; ++qi) {
        const int qt = (qi == 0) ? xA : xB;
        if (qi == 0 && tg > tmaxA) continue;
        const int q0q = qt * 64;

        // ---- S = (scaled Q) K^T ----
        f32x4 s[4];
#pragma unroll
        for (int nt = 0; nt < 4; ++nt) s[nt] = (f32x4){0.f, 0.f, 0.f, 0.f};
#pragma unroll
        for (int c = 0; c < 2; ++c) {
#pragma unroll
          for (int nt = 0; nt < 4; ++nt) {
            const int kr = nt * 16 + lo;
            bf16x8 b = *(const bf16x8*)&sm.t.K[g][kr][SWZ(kr, c * 32 + hi * 8)];
            s[nt] = __builtin_amdgcn_mfma_f32_16x16x32_bf16(aq[qi][c], b, s[nt], 0, 0, 0);
          }
        }

        // ---- causal mask: diagonal tile only ----
        if (causal && tg == qt) {
#pragma unroll
          for (int nt = 0; nt < 4; ++nt) {
            const int kvg = k0 + nt * 16 + lo;
#pragma unroll
            for (int r = 0; r < 4; ++r) {
              const int qg = q0q + w4 * 16 + hi * 4 + r;
              if (kvg > qg) s[nt][r] = -INFINITY;
            }
          }
        }

        // ---- online softmax (exp2 domain), 16-lane butterfly ----
#pragma unroll
        for (int r = 0; r < 4; ++r) {
          float mx = fmaxf(fmaxf(s[0][r], s[1][r]), fmaxf(s[2][r], s[3][r]));
          mx = fmaxf(mx, __shfl_xor(mx, 1));
          mx = fmaxf(mx, __shfl_xor(mx, 2));
          mx = fmaxf(mx, __shfl_xor(mx, 4));
          mx = fmaxf(mx, __shfl_xor(mx, 8));
          const float mnew = fmaxf(m_run[qi][r], mx);
          const float fac  = exp2f(m_run[qi][r] - mnew);
          float ps = 0.f;
#pragma unroll
          for (int nt = 0; nt < 4; ++nt) {
            const float p = exp2f(s[nt][r] - mnew);
            s[nt][r] = p;
            ps += p;
          }
          ps += __shfl_xor(ps, 1);
          ps += __shfl_xor(ps, 2);
          ps += __shfl_xor(ps, 4);
          ps += __shfl_xor(ps, 8);
          l_run[qi][r] = l_run[qi][r] * fac + ps;
          m_run[qi][r] = mnew;
#pragma unroll
          for (int nt = 0; nt < 4; ++nt) acc[qi][nt][r] *= fac;
        }

        // ---- P -> LDS (wave-private rows) ----
        asm volatile("s_waitcnt lgkmcnt(0)" ::: "memory");
#pragma unroll
        for (int nt = 0; nt < 4; ++nt)
#pragma unroll
          for (int r = 0; r < 4; ++r) {
            const int q = w4 * 16 + hi * 4 + r;
            sm.t.P[g][q][SWZ(q, nt * 16 + lo)] = (__bf16)s[nt][r];
          }
        asm volatile("s_waitcnt lgkmcnt(0)" ::: "memory");

        // ---- O += P V ----
#pragma unroll
        for (int c = 0; c < 2; ++c) {
          const int pr = w4 * 16 + lo;
          bf16x8 pa = *(const bf16x8*)&sm.t.P[g][pr][SWZ(pr, c * 32 + hi * 8)];
#pragma unroll
          for (int nt = 0; nt < 4; ++nt) {
            const int vr2 = nt * 16 + lo;
            bf16x8 vb = *(const bf16x8*)&sm.t.V[g][vr2][SWZ(vr2, c * 32 + hi * 8)];
            acc[qi][nt] = __builtin_amdgcn_mfma_f32_16x16x32_bf16(pa, vb, acc[qi][nt], 0, 0, 0);
          }
        }
      }
    }

    __syncthreads();   // group's waves done reading tile tg
    if (pf) wr();      // regs -> LDS for tile tg+2
    __syncthreads();
  }

  // ---- merge the two KV-parity partials, then write O ----
  __syncthreads();
  const int cidx = w4 * 64 + lane;
  if (g == 1) {
#pragma unroll
    for (int qi = 0; qi < 2; ++qi) {
#pragma unroll
      for (int nt = 0; nt < 4; ++nt)
#pragma unroll
        for (int r = 0; r < 4; ++r)
          sm.mrg[nt * 4 + r][qi][cidx] = acc[qi][nt][r];
#pragma unroll
      for (int r = 0; r < 4; ++r) {
        sm.mrg[16 + r][qi][cidx] = m_run[qi][r];
        sm.mrg[20 + r][qi][cidx] = l_run[qi][r];
      }
    }
  }
  __syncthreads();
  if (g == 0) {
#pragma unroll
    for (int qi = 0; qi < 2; ++qi) {
      const int q0q = ((qi == 0) ? xA : xB) * 64;
      float f1[4], f2[4], linv[4];
#pragma unroll
      for (int r = 0; r < 4; ++r) {
        const float m2 = sm.mrg[16 + r][qi][cidx];
        const float l2 = sm.mrg[20 + r][qi][cidx];
        const float m1 = m_run[qi][r], l1 = l_run[qi][r];
        const float mm = fmaxf(m1, m2);
        const float e1 = (m1 == -INFINITY) ? 0.f : exp2f(m1 - mm);
        const float e2 = (m2 == -INFINITY) ? 0.f : exp2f(m2 - mm);
        f1[r] = e1; f2[r] = e2;
        linv[r] = 1.f / (l1 * e1 + l2 * e2);
      }
      const int qrow = q0q + w4 * 16 + hi * 4;
#pragma unroll
      for (int nt = 0; nt < 4; ++nt)
#pragma unroll
        for (int r = 0; r < 4; ++r) {
          const float a2 = sm.mrg[nt * 4 + r][qi][cidx];
          Ob[(long)(qrow + r) * sN + nt * 16 + lo] =
            (acc[qi][nt][r] * f1[r] + a2 * f2[r]) * linv[r];
        }
    }
  }
}

extern "C" void kernel_launch(void* const* d_in, const int* in_sizes, int n_in,
                              void* d_out, int out_size, void* d_ws, size_t ws_size,
                              hipStream_t stream) {
  const float* q = (const float*)d_in[0];
  const float* k = (const float*)d_in[1];
  const float* v = (const float*)d_in[2];
  const int* causal = (const int*)d_in[3];
  float* out = (float*)d_out;
  const int B = 2, N = 2048, H = 16;
  dim3 grid((NQT / 2) * B * H);   // 512 blocks
  fattn_fwd<<<grid, dim3(512), 0, stream>>>(q, k, v, causal, out, B, N, H);
}

// Round 4
// 159.748 us; speedup vs baseline: 2.3020x; 2.3020x over previous
//
#include <hip/hip_runtime.h>
#include <hip/hip_bf16.h>
#include <math.h>

typedef __bf16 bf16x8 __attribute__((ext_vector_type(8)));
typedef __bf16 bf16x4 __attribute__((ext_vector_type(4)));
typedef float  f32x4  __attribute__((ext_vector_type(4)));

#define HD  64
#define NQT 32   // N / 64
#define LDK 72   // 144B stride: b128 reads 16B-aligned, ~2-way banks
#define LDV 68   // 136B stride: b64/b32 ops 8B-aligned
#define LDP 72

__global__ __launch_bounds__(256, 4)
void fattn_fwd(const float* __restrict__ Q, const float* __restrict__ K,
               const float* __restrict__ V, const int* __restrict__ causal_p,
               float* __restrict__ O, int B, int N, int H) {
  __shared__ alignas(16) __bf16 Kl[64][LDK];   // K[kv][d]
  __shared__ alignas(16) __bf16 Vl[64][LDV];   // V^T[d][kv]
  __shared__ alignas(16) __bf16 Pl[64][LDP];   // P[q][kv], wave-private rows

  const int tid  = threadIdx.x;
  const int wave = tid >> 6;
  const int lane = tid & 63;
  const int lo = lane & 15, hi = lane >> 4;

  // LPT: heaviest q-tiles (x=31) dispatched first; 1-unit tiles backfill tail
  const int x  = (NQT - 1) - (blockIdx.x >> 5);
  const int bh = blockIdx.x & 31;
  const int bb = bh / H, hh = bh - bb * H;

  const int causal = causal_p[0];
  const int sN = H * HD;

  const float* Qb = Q + (long)bb * N * sN + hh * HD;
  const float* Kb = K + (long)bb * N * sN + hh * HD;
  const float* Vb = V + (long)bb * N * sN + hh * HD;
  float*       Ob = O + (long)bb * N * sN + hh * HD;

  const int q0 = x * 64;
  const int ntile = causal ? (x + 1) : NQT;

  // ---- Q fragment, scaled by 1/sqrt(d)*log2(e) (exp2-domain softmax) ----
  const float qscale = 0.125f * 1.44269504088896340736f;
  bf16x8 aq[2];
  {
    const float* qp = Qb + (long)(q0 + wave * 16 + lo) * sN;
#pragma unroll
    for (int c = 0; c < 2; ++c) {
      f32x4 x0 = *(const f32x4*)(qp + c * 32 + hi * 8);
      f32x4 x1 = *(const f32x4*)(qp + c * 32 + hi * 8 + 4);
      bf16x8 a;
#pragma unroll
      for (int j = 0; j < 4; ++j) {
        a[j]     = (__bf16)(x0[j] * qscale);
        a[j + 4] = (__bf16)(x1[j] * qscale);
      }
      aq[c] = a;
    }
  }

  f32x4 acc[4];
  float m_run[4], l_run[4];
#pragma unroll
  for (int i = 0; i < 4; ++i) {
    acc[i] = (f32x4){0.f, 0.f, 0.f, 0.f};
    m_run[i] = -INFINITY;
    l_run[i] = 0.f;
  }

  // ---- staging: global -> regs (issue), regs -> LDS (wr) ----
  f32x4 kreg[4], vreg[4];
  auto issue = [&](int tt) {
    const int k0 = tt * 64;
#pragma unroll
    for (int i = 0; i < 4; ++i) {
      const int fl = tid + i * 256;
      const int r = fl >> 4, c4 = (fl & 15) * 4;
      kreg[i] = *(const f32x4*)(Kb + (long)(k0 + r) * sN + c4);
    }
    // V: lane owns a 4x4 (kv x d) block -> free in-register transpose
    const float* vrow = Vb + (long)(k0 + wave * 16 + hi * 4) * sN + lo * 4;
#pragma unroll
    for (int q = 0; q < 4; ++q) vreg[q] = *(const f32x4*)(vrow + (long)q * sN);
  };
  auto wr = [&]() {
#pragma unroll
    for (int i = 0; i < 4; ++i) {
      const int fl = tid + i * 256;
      const int r = fl >> 4, c4 = (fl & 15) * 4;
      bf16x4 kb;
#pragma unroll
      for (int j = 0; j < 4; ++j) kb[j] = (__bf16)kreg[i][j];
      *(bf16x4*)&Kl[r][c4] = kb;
    }
#pragma unroll
    for (int j = 0; j < 4; ++j) {
      bf16x4 vv;
#pragma unroll
      for (int q = 0; q < 4; ++q) vv[q] = (__bf16)vreg[q][j];
      *(bf16x4*)&Vl[lo * 4 + j][wave * 16 + hi * 4] = vv;
    }
  };

  // prologue: stage tile 0
  issue(0);
  wr();
  __syncthreads();

  for (int t = 0; t < ntile; ++t) {
    const bool pf = (t + 1 < ntile);
    if (pf) issue(t + 1);   // HBM latency hides under compute below
    const int k0 = t * 64;

    // ---- S = (scaled Q) K^T ----
    f32x4 s[4];
#pragma unroll
    for (int nt = 0; nt < 4; ++nt) s[nt] = (f32x4){0.f, 0.f, 0.f, 0.f};
#pragma unroll
    for (int c = 0; c < 2; ++c) {
#pragma unroll
      for (int nt = 0; nt < 4; ++nt) {
        bf16x8 b = *(const bf16x8*)&Kl[nt * 16 + lo][c * 32 + hi * 8];
        s[nt] = __builtin_amdgcn_mfma_f32_16x16x32_bf16(aq[c], b, s[nt], 0, 0, 0);
      }
    }

    // ---- causal mask: diagonal tile only ----
    if (causal && t == x) {
#pragma unroll
      for (int nt = 0; nt < 4; ++nt) {
        const int kvg = k0 + nt * 16 + lo;
#pragma unroll
        for (int r = 0; r < 4; ++r) {
          const int qg = q0 + wave * 16 + hi * 4 + r;
          if (kvg > qg) s[nt][r] = -INFINITY;
        }
      }
    }

    // ---- online softmax (exp2 domain), 16-lane butterfly ----
#pragma unroll
    for (int r = 0; r < 4; ++r) {
      float mx = fmaxf(fmaxf(s[0][r], s[1][r]), fmaxf(s[2][r], s[3][r]));
      mx = fmaxf(mx, __shfl_xor(mx, 1));
      mx = fmaxf(mx, __shfl_xor(mx, 2));
      mx = fmaxf(mx, __shfl_xor(mx, 4));
      mx = fmaxf(mx, __shfl_xor(mx, 8));
      const float mnew = fmaxf(m_run[r], mx);
      const float fac  = exp2f(m_run[r] - mnew);
      float ps = 0.f;
#pragma unroll
      for (int nt = 0; nt < 4; ++nt) {
        const float p = exp2f(s[nt][r] - mnew);
        s[nt][r] = p;
        ps += p;
      }
      ps += __shfl_xor(ps, 1);
      ps += __shfl_xor(ps, 2);
      ps += __shfl_xor(ps, 4);
      ps += __shfl_xor(ps, 8);
      l_run[r] = l_run[r] * fac + ps;
      m_run[r] = mnew;
#pragma unroll
      for (int nt = 0; nt < 4; ++nt) acc[nt][r] *= fac;
    }

    // ---- P -> LDS (wave-private rows; wave-local ordering only) ----
    asm volatile("s_waitcnt lgkmcnt(0)" ::: "memory");
#pragma unroll
    for (int nt = 0; nt < 4; ++nt)
#pragma unroll
      for (int r = 0; r < 4; ++r)
        Pl[wave * 16 + hi * 4 + r][nt * 16 + lo] = (__bf16)s[nt][r];
    asm volatile("s_waitcnt lgkmcnt(0)" ::: "memory");

    // ---- O += P V ----
#pragma unroll
    for (int c = 0; c < 2; ++c) {
      bf16x8 pa = *(const bf16x8*)&Pl[wave * 16 + lo][c * 32 + hi * 8];
#pragma unroll
      for (int nt = 0; nt < 4; ++nt) {
        const __bf16* vp = &Vl[nt * 16 + lo][c * 32 + hi * 8];
        bf16x4 v0 = *(const bf16x4*)vp;
        bf16x4 v1 = *(const bf16x4*)(vp + 4);
        bf16x8 vb;
#pragma unroll
        for (int j = 0; j < 4; ++j) { vb[j] = v0[j]; vb[j + 4] = v1[j]; }
        acc[nt] = __builtin_amdgcn_mfma_f32_16x16x32_bf16(pa, vb, acc[nt], 0, 0, 0);
      }
    }

    __syncthreads();   // all waves done reading Kl/Vl tile t
    if (pf) wr();      // regs -> LDS for tile t+1
    __syncthreads();   // staging visible
  }

  // ---- epilogue: O = acc / l ----
  {
    const int qrow = q0 + wave * 16 + hi * 4;
#pragma unroll
    for (int nt = 0; nt < 4; ++nt) {
#pragma unroll
      for (int r = 0; r < 4; ++r) {
        Ob[(long)(qrow + r) * sN + nt * 16 + lo] = acc[nt][r] / l_run[r];
      }
    }
  }
}

extern "C" void kernel_launch(void* const* d_in, const int* in_sizes, int n_in,
                              void* d_out, int out_size, void* d_ws, size_t ws_size,
                              hipStream_t stream) {
  const float* q = (const float*)d_in[0];
  const float* k = (const float*)d_in[1];
  const float* v = (const float*)d_in[2];
  const int* causal = (const int*)d_in[3];
  float* out = (float*)d_out;
  const int B = 2, N = 2048, H = 16;
  dim3 grid(NQT * B * H);   // 1024 blocks, heavy-first mapping inside kernel
  fattn_fwd<<<grid, dim3(256), 0, stream>>>(q, k, v, causal, out, B, N, H);
}

// Round 6
// 142.638 us; speedup vs baseline: 2.5781x; 1.1199x over previous
//
#include <hip/hip_runtime.h>
#include <hip/hip_bf16.h>
#include <math.h>

typedef __bf16 bf16x8 __attribute__((ext_vector_type(8)));
typedef __bf16 bf16x4 __attribute__((ext_vector_type(4)));
typedef __bf16 bf16x2 __attribute__((ext_vector_type(2)));
typedef float  f32x4  __attribute__((ext_vector_type(4)));
typedef float  f32x16 __attribute__((ext_vector_type(16)));
typedef unsigned int u32;
typedef unsigned int u32x4 __attribute__((ext_vector_type(4)));

#define HD   64
#define NQB  16        // 2048 / 128 q-rows per block
#define MNEG (-1e30f)  // finite "-inf": exp2f(MNEG - x) == 0, no NaN possible
// XOR swizzles (element-space) for 128B-stride rows; write & read sides agree
#define KSW(r, c) ((c) ^ (((r) & 7) << 3))
#define VSW(r, c) ((c) ^ ((((r) >> 2) & 7) << 3))

static __device__ __forceinline__ u32 pkbf(float a, float b) {
  bf16x2 t; t[0] = (__bf16)a; t[1] = (__bf16)b;
  return __builtin_bit_cast(u32, t);
}

__global__ __launch_bounds__(256, 2)
void fattn_fwd(const float* __restrict__ Q, const float* __restrict__ K,
               const float* __restrict__ V, const int* __restrict__ causal_p,
               float* __restrict__ O, int B, int N, int H) {
  __shared__ alignas(16) __bf16 Kl[64][64];   // K[kv][d], swizzled cols
  __shared__ alignas(16) __bf16 Vt[64][64];   // V^T[d][kv], swizzled cols

  const int tid  = threadIdx.x;
  const int wave = tid >> 6;
  const int lane = tid & 63;
  const int l31  = lane & 31;
  const int h    = lane >> 5;        // 32-lane half
  const int lo16 = lane & 15, hi4 = lane >> 4;

  // LPT: heaviest q-blocks first; bh fastest -> neighbors share K/V in L2
  const int x  = (NQB - 1) - ((int)blockIdx.x >> 5);
  const int bh = blockIdx.x & 31;
  const int bb = bh / H, hh = bh - bb * H;

  const int causal = causal_p[0];
  const int sN = H * HD;

  const float* Qb = Q + (long)bb * N * sN + hh * HD;
  const float* Kb = K + (long)bb * N * sN + hh * HD;
  const float* Vb = V + (long)bb * N * sN + hh * HD;
  float*       Ob = O + (long)bb * N * sN + hh * HD;

  const int q0w   = x * 128 + wave * 32;          // this wave's q-rows
  const int ntile = causal ? (2 * x + 2) : (2 * NQB);

  // ---- Q fragments (B-operand: col=q=lane&31, k = h*8+0..7 per d-slice) ----
  const float qscale = 0.125f * 1.44269504088896340736f;  // 1/sqrt(64)*log2e
  bf16x8 aq[4];
  {
    const float* qrow = Qb + (long)(q0w + l31) * sN;
#pragma unroll
    for (int ds = 0; ds < 4; ++ds) {
      f32x4 x0 = *(const f32x4*)(qrow + ds * 16 + h * 8);
      f32x4 x1 = *(const f32x4*)(qrow + ds * 16 + h * 8 + 4);
      bf16x8 a;
#pragma unroll
      for (int j = 0; j < 4; ++j) {
        a[j]     = (__bf16)(x0[j] * qscale);
        a[j + 4] = (__bf16)(x1[j] * qscale);
      }
      aq[ds] = a;
    }
  }

  // O^T accumulators: col=q=lane&31 (one q per lane), rows=d
  f32x16 accA, accB;
#pragma unroll
  for (int j = 0; j < 16; ++j) { accA[j] = 0.f; accB[j] = 0.f; }
  float m_run = MNEG, l_run = 0.f;

  // ---- staging: global f32 -> regs (issue), regs -> bf16 LDS (wr) ----
  f32x4 kreg[4], vreg[4];
  auto issue = [&](int tt) {
    const int k0 = tt * 64;
#pragma unroll
    for (int i = 0; i < 4; ++i) {
      const int fl = tid + i * 256;
      const int r = fl >> 4, c4 = (fl & 15) * 4;
      kreg[i] = *(const f32x4*)(Kb + (long)(k0 + r) * sN + c4);
    }
    // V: lane owns 4x4 (kv x d) block -> free in-register transpose
    const float* vrow = Vb + (long)(k0 + wave * 16 + hi4 * 4) * sN + lo16 * 4;
#pragma unroll
    for (int q = 0; q < 4; ++q) vreg[q] = *(const f32x4*)(vrow + (long)q * sN);
  };
  auto wr = [&]() {
#pragma unroll
    for (int i = 0; i < 4; ++i) {
      const int fl = tid + i * 256;
      const int r = fl >> 4, c4 = (fl & 15) * 4;
      bf16x4 kb;
#pragma unroll
      for (int j = 0; j < 4; ++j) kb[j] = (__bf16)kreg[i][j];
      *(bf16x4*)&Kl[r][KSW(r, c4)] = kb;
    }
    const int kv0 = wave * 16 + hi4 * 4;
#pragma unroll
    for (int j = 0; j < 4; ++j) {
      const int d = lo16 * 4 + j;
      bf16x4 vv;
#pragma unroll
      for (int q = 0; q < 4; ++q) vv[q] = (__bf16)vreg[q][j];
      *(bf16x4*)&Vt[d][VSW(d, kv0)] = vv;
    }
  };

  issue(0);
  wr();
  __syncthreads();

  for (int t = 0; t < ntile; ++t) {
    const bool pf = (t + 1 < ntile);
    if (pf) issue(t + 1);            // T14: loads in flight under compute
    const int k0 = t * 64;

    // ---- S^T = K (A, rows=kv) x Q^T (B, cols=q) ----
    f32x16 p0, p1;
#pragma unroll
    for (int j = 0; j < 16; ++j) { p0[j] = 0.f; p1[j] = 0.f; }
#pragma unroll
    for (int ds = 0; ds < 4; ++ds) {
      const int cc = ds * 16 + h * 8;
      bf16x8 ka = *(const bf16x8*)&Kl[l31][KSW(l31, cc)];
      p0 = __builtin_amdgcn_mfma_f32_32x32x16_bf16(ka, aq[ds], p0, 0, 0, 0);
      bf16x8 kb2 = *(const bf16x8*)&Kl[32 + l31][KSW(32 + l31, cc)];
      p1 = __builtin_amdgcn_mfma_f32_32x32x16_bf16(kb2, aq[ds], p1, 0, 0, 0);
    }

    // ---- causal mask (last two tiles of the q-block only) ----
    if (causal && t >= ntile - 2) {
      const int qg = q0w + l31;
#pragma unroll
      for (int reg = 0; reg < 16; ++reg) {
        const int crow = (reg & 3) + 8 * (reg >> 2) + 4 * h;
        if (k0 + crow > qg)      p0[reg] = MNEG;
        if (k0 + 32 + crow > qg) p1[reg] = MNEG;
      }
    }

    // ---- online softmax: in-lane trees + one cross-half shuffle ----
    float t8[8];
#pragma unroll
    for (int j = 0; j < 8; ++j)
      t8[j] = fmaxf(fmaxf(p0[j], p0[j + 8]), fmaxf(p1[j], p1[j + 8]));
#pragma unroll
    for (int stp = 4; stp > 0; stp >>= 1)
#pragma unroll
      for (int j = 0; j < stp; ++j) t8[j] = fmaxf(t8[j], t8[j + stp]);
    const float mx = fmaxf(t8[0], __shfl_xor(t8[0], 32));
    const float mnew = fmaxf(m_run, mx);
    const float fac  = exp2f(m_run - mnew);   // finite-domain; first tile: 0
#pragma unroll
    for (int j = 0; j < 16; ++j) {
      p0[j] = exp2f(p0[j] - mnew);            // masked MNEG -> 0
      p1[j] = exp2f(p1[j] - mnew);
    }
    float s8[8];
#pragma unroll
    for (int j = 0; j < 8; ++j)
      s8[j] = (p0[j] + p0[j + 8]) + (p1[j] + p1[j + 8]);
#pragma unroll
    for (int stp = 4; stp > 0; stp >>= 1)
#pragma unroll
      for (int j = 0; j < stp; ++j) s8[j] += s8[j + stp];
    const float ps = s8[0] + __shfl_xor(s8[0], 32);
    l_run = l_run * fac + ps;
    m_run = mnew;
#pragma unroll
    for (int j = 0; j < 16; ++j) { accA[j] *= fac; accB[j] *= fac; }

    // ---- P^T B-fragments in-register: pack to bf16x2 words, then exchange
    //      halves with verified-semantics shfl_xor(32) + selects ----
    u32 W0[8], W1[8];
#pragma unroll
    for (int tt = 0; tt < 8; ++tt) {
      W0[tt] = pkbf(p0[2 * tt], p0[2 * tt + 1]);
      W1[tt] = pkbf(p1[2 * tt], p1[2 * tt + 1]);
    }
    // For word-pair (wa=W[i], wb=W[i+2]):
    //   dlo: h=0 -> own wa        ; h=1 -> other half's wa
    //   dhi: h=0 -> other half's wb... (derived: lane h needs own family and
    //   the other half's SAME family; one shuffle of the cross term suffices)
    auto mkpair = [&](u32 wa, u32 wb, u32& dlo, u32& dhi) {
      const u32 gsel = h ? wa : wb;             // what the other half needs
      const u32 f = (u32)__shfl_xor((int)gsel, 32);
      dlo = h ? f : wa;                         // h0: own wa ; h1: wa@h0
      dhi = h ? wb : f;                         // h0: wb@h1  ; h1: own wb
    };
    bf16x8 pa[4];
    {
      u32 d0, d1, d2, d3;
      mkpair(W0[0], W0[2], d0, d2); mkpair(W0[1], W0[3], d1, d3);
      pa[0] = __builtin_bit_cast(bf16x8, (u32x4){d0, d1, d2, d3});
      mkpair(W0[4], W0[6], d0, d2); mkpair(W0[5], W0[7], d1, d3);
      pa[1] = __builtin_bit_cast(bf16x8, (u32x4){d0, d1, d2, d3});
      mkpair(W1[0], W1[2], d0, d2); mkpair(W1[1], W1[3], d1, d3);
      pa[2] = __builtin_bit_cast(bf16x8, (u32x4){d0, d1, d2, d3});
      mkpair(W1[4], W1[6], d0, d2); mkpair(W1[5], W1[7], d1, d3);
      pa[3] = __builtin_bit_cast(bf16x8, (u32x4){d0, d1, d2, d3});
    }

    // ---- O^T += V^T (A, rows=d) x P^T (B, cols=q) ----
#pragma unroll
    for (int ks = 0; ks < 4; ++ks) {
      bf16x8 va = *(const bf16x8*)&Vt[l31][VSW(l31, ks * 16 + h * 8)];
      accA = __builtin_amdgcn_mfma_f32_32x32x16_bf16(va, pa[ks], accA, 0, 0, 0);
    }
#pragma unroll
    for (int ks = 0; ks < 4; ++ks) {
      bf16x8 va = *(const bf16x8*)&Vt[32 + l31][VSW(32 + l31, ks * 16 + h * 8)];
      accB = __builtin_amdgcn_mfma_f32_32x32x16_bf16(va, pa[ks], accB, 0, 0, 0);
    }

    __syncthreads();   // done reading Kl/Vt tile t
    if (pf) wr();      // regs -> LDS tile t+1
    __syncthreads();
  }

  // ---- epilogue: O[q][d] = acc / l ; lane owns q, d = j + 8g + 4h ----
  {
    const float linv = 1.0f / l_run;
    float* orow = Ob + (long)(q0w + l31) * sN;
#pragma unroll
    for (int g = 0; g < 4; ++g) {
      f32x4 o0, o1;
#pragma unroll
      for (int j = 0; j < 4; ++j) {
        o0[j] = accA[4 * g + j] * linv;
        o1[j] = accB[4 * g + j] * linv;
      }
      *(f32x4*)(orow + 8 * g + 4 * h) = o0;
      *(f32x4*)(orow + 32 + 8 * g + 4 * h) = o1;
    }
  }
}

extern "C" void kernel_launch(void* const* d_in, const int* in_sizes, int n_in,
                              void* d_out, int out_size, void* d_ws, size_t ws_size,
                              hipStream_t stream) {
  const float* q = (const float*)d_in[0];
  const float* k = (const float*)d_in[1];
  const float* v = (const float*)d_in[2];
  const int* causal = (const int*)d_in[3];
  float* out = (float*)d_out;
  const int B = 2, N = 2048, H = 16;
  dim3 grid(NQB * B * H);   // 512 blocks of 256 threads (4 waves x 32 q-rows)
  fattn_fwd<<<grid, dim3(256), 0, stream>>>(q, k, v, causal, out, B, N, H);
}